// Round 4
// baseline (472.725 us; speedup 1.0000x reference)
//
#include <hip/hip_runtime.h>
#include <hip/hip_bf16.h>

constexpr int N_NODES = 500000;
constexpr int N_Q     = 500000;
constexpr int H       = 8;
constexpr int FEAT    = 64;                      // H * MH
constexpr int NT      = (N_NODES + 63) / 64;     // 7813 node tiles

// ws layout (ints): perm[N_Q] | cnt[NT] | ofs[NT] | cursor[NT]

// ---------------------------------------------------------------------------
// Sort chain: counting sort of queries by node tile (j >> 6).
// ---------------------------------------------------------------------------
__global__ __launch_bounds__(256) void k_zero(int* __restrict__ cnt)
{
    const int i = blockIdx.x * 256 + threadIdx.x;
    if (i < NT) cnt[i] = 0;
}

__global__ __launch_bounds__(256) void k_hist(const int* __restrict__ k_idx,
                                              int* __restrict__ cnt)
{
    const int q = blockIdx.x * 256 + threadIdx.x;
    if (q < N_Q) atomicAdd(&cnt[k_idx[q] >> 6], 1);
}

// single-block exclusive scan over NT (<= 8*1024) elements
__global__ __launch_bounds__(1024) void k_scan(const int* __restrict__ cnt,
                                               int* __restrict__ ofs,
                                               int* __restrict__ cursor)
{
    __shared__ int lds[1024];
    __shared__ int running;
    const int t = threadIdx.x;
    if (t == 0) running = 0;
    __syncthreads();
    for (int base = 0; base < NT; base += 1024) {
        const int i = base + t;
        const int v = (i < NT) ? cnt[i] : 0;
        lds[t] = v;
        __syncthreads();
        for (int off = 1; off < 1024; off <<= 1) {
            const int x = (t >= off) ? lds[t - off] : 0;
            __syncthreads();
            lds[t] += x;
            __syncthreads();
        }
        const int excl = lds[t] - v + running;
        if (i < NT) { ofs[i] = excl; cursor[i] = excl; }
        const int total = lds[1023];
        __syncthreads();
        if (t == 0) running += total;
        __syncthreads();
    }
}

__global__ __launch_bounds__(256) void k_scatter(const int* __restrict__ k_idx,
                                                 int* __restrict__ cursor,
                                                 int* __restrict__ perm)
{
    const int q = blockIdx.x * 256 + threadIdx.x;
    if (q < N_Q) {
        const int j = k_idx[q];
        const int p = atomicAdd(&cursor[j >> 6], 1);
        perm[p] = q | ((j & 63) << 19);          // q < 2^19, jloc in 6 bits
    }
}

// ---------------------------------------------------------------------------
// Fused main: block b owns node tile [b*64, b*64+64).
//  - stage pos/neg pk columns for the tile into LDS (coalesced float4 rows)
//  - process this tile's queries: thread = (query-in-batch, head)
//    q_phi: 256B-granule gather (full line use); deg: j-sorted sequential;
//    out: scattered 32B stores by q.
// LDS pad 65: dot-read bank = (f + jloc) % 32 -> ~2-way (free).
// ---------------------------------------------------------------------------
__global__ __launch_bounds__(256) void k_main(
    const float* __restrict__ q_phi,
    const float* __restrict__ pk_pos,
    const float* __restrict__ pk_neg,
    const float* __restrict__ deg_pos,
    const float* __restrict__ deg_neg,
    const int*   __restrict__ perm,
    const int*   __restrict__ ofs,
    const int*   __restrict__ cnt,
    float*       __restrict__ out)
{
    __shared__ float lp[64 * 65];
    __shared__ float ln[64 * 65];

    const int t    = threadIdx.x;
    const int b    = blockIdx.x;
    const int n0   = b * 64;
    const int nrem = min(64, N_NODES - n0);

    // ---- stage tile: 64 feature-rows x 64 nodes, pos & neg ----
    {
        const int n4 = (t & 15) * 4;             // 0,4,...,60
        const int fb = t >> 4;                   // 0..15
        for (int it = 0; it < 4; ++it) {
            const int f = fb + it * 16;
            const size_t off = (size_t)f * N_NODES + n0 + n4;
            float4 vp = make_float4(0.f, 0.f, 0.f, 0.f);
            float4 vn = make_float4(0.f, 0.f, 0.f, 0.f);
            if (n4 + 3 < nrem) {
                vp = *(const float4*)(pk_pos + off);
                vn = *(const float4*)(pk_neg + off);
            } else if (n4 < nrem) {
                vp.x = pk_pos[off]; vn.x = pk_neg[off];
                if (n4 + 1 < nrem) { vp.y = pk_pos[off + 1]; vn.y = pk_neg[off + 1]; }
                if (n4 + 2 < nrem) { vp.z = pk_pos[off + 2]; vn.z = pk_neg[off + 2]; }
            }
            float* wp = &lp[f * 65 + n4];
            float* wn = &ln[f * 65 + n4];
            wp[0] = vp.x; wp[1] = vp.y; wp[2] = vp.z; wp[3] = vp.w;
            wn[0] = vn.x; wn[1] = vn.y; wn[2] = vn.z; wn[3] = vn.w;
        }
    }
    __syncthreads();

    // ---- process this tile's queries, 32 per iteration ----
    const int start = ofs[b];
    const int count = cnt[b];
    const int qi = t >> 3;                       // 0..31
    const int h  = t & 7;

    for (int base = 0; base < count; base += 32) {
        const int k = base + qi;
        if (k < count) {
            const int v  = perm[start + k];
            const int q  = v & 0x7FFFF;
            const int jl = v >> 19;

            const float4* qp = (const float4*)(q_phi + (size_t)q * FEAT + h * 8);
            const float4 a0 = qp[0], a1 = qp[1];

            const float* rp = &lp[(h * 8) * 65 + jl];
            const float* rn = &ln[(h * 8) * 65 + jl];

            float sp = a0.x * rp[0]       + a0.y * rp[65]      + a0.z * rp[130]
                     + a0.w * rp[195]     + a1.x * rp[260]     + a1.y * rp[325]
                     + a1.z * rp[390]     + a1.w * rp[455];
            float sn = a0.x * rn[0]       + a0.y * rn[65]      + a0.z * rn[130]
                     + a0.w * rn[195]     + a1.x * rn[260]     + a1.y * rn[325]
                     + a1.z * rn[390]     + a1.w * rn[455];

            const int j = n0 + jl;
            const float dp = fmaxf(deg_pos[(size_t)j * H + h], 1.0f);
            const float dn = fmaxf(deg_neg[(size_t)j * H + h], 1.0f);

            const size_t o = (size_t)q * H + h;
            __builtin_nontemporal_store(sp / dp, &out[o]);
            __builtin_nontemporal_store(sn / dn, &out[(size_t)N_Q * H + o]);
        }
    }
}

// ---------------------------------------------------------------------------
// Fallback (R0 path) if workspace is too small.
// ---------------------------------------------------------------------------
__global__ __launch_bounds__(256, 4) void iskde_gather_kernel(
    const float* __restrict__ q_phi,
    const float* __restrict__ pk_pos,
    const float* __restrict__ pk_neg,
    const float* __restrict__ deg_pos,
    const float* __restrict__ deg_neg,
    const int*   __restrict__ k_idx,
    float*       __restrict__ out)
{
    const int wave_in_blk = threadIdx.x >> 6;
    const int lane        = threadIdx.x & 63;
    const int q           = blockIdx.x * 4 + wave_in_blk;
    if (q >= N_Q) return;

    const int j = k_idx[q];
    const float qv = q_phi[(size_t)q * FEAT + lane];
    const size_t col = (size_t)lane * (size_t)N_NODES + (size_t)j;
    const float pv = pk_pos[col];
    const float nv = pk_neg[col];

    float sp = qv * pv;
    float sn = qv * nv;
    sp += __shfl_xor(sp, 1, 64);
    sn += __shfl_xor(sn, 1, 64);
    sp += __shfl_xor(sp, 2, 64);
    sn += __shfl_xor(sn, 2, 64);
    sp += __shfl_xor(sp, 4, 64);
    sn += __shfl_xor(sn, 4, 64);

    if ((lane & 7) == 0) {
        const int h = lane >> 3;
        const float dp = fmaxf(deg_pos[(size_t)j * H + h], 1.0f);
        const float dn = fmaxf(deg_neg[(size_t)j * H + h], 1.0f);
        const size_t o = (size_t)q * H + h;
        out[o]                   = sp / dp;
        out[(size_t)N_Q * H + o] = sn / dn;
    }
}

extern "C" void kernel_launch(void* const* d_in, const int* in_sizes, int n_in,
                              void* d_out, int out_size, void* d_ws, size_t ws_size,
                              hipStream_t stream) {
    const float* q_phi   = (const float*)d_in[0];
    const float* pk_pos  = (const float*)d_in[1];
    const float* pk_neg  = (const float*)d_in[2];
    const float* deg_pos = (const float*)d_in[3];
    const float* deg_neg = (const float*)d_in[4];
    const int*   k_idx   = (const int*)d_in[5];
    float*       out     = (float*)d_out;

    const size_t need = ((size_t)N_Q + 3 * (size_t)NT) * sizeof(int);  // ~2.1 MB

    if (ws_size >= need) {
        int* perm   = (int*)d_ws;
        int* cnt    = perm + N_Q;
        int* ofs    = cnt + NT;
        int* cursor = ofs + NT;

        const int gq = (N_Q + 255) / 256;        // 1954
        const int gt = (NT + 255) / 256;         // 31

        k_zero<<<gt, 256, 0, stream>>>(cnt);
        k_hist<<<gq, 256, 0, stream>>>(k_idx, cnt);
        k_scan<<<1, 1024, 0, stream>>>(cnt, ofs, cursor);
        k_scatter<<<gq, 256, 0, stream>>>(k_idx, cursor, perm);
        k_main<<<NT, 256, 0, stream>>>(q_phi, pk_pos, pk_neg,
                                       deg_pos, deg_neg, perm, ofs, cnt, out);
    } else {
        const int blocks = (N_Q + 3) / 4;
        iskde_gather_kernel<<<blocks, 256, 0, stream>>>(
            q_phi, pk_pos, pk_neg, deg_pos, deg_neg, k_idx, out);
    }
}